// Round 1
// 296.355 us; speedup vs baseline: 1.0112x; 1.0112x over previous
//
#include <hip/hip_runtime.h>

// out[b, i, j] = x[b, i, i+j] if i+j < L else 0
// B=4, L=4096, LIMIT=256. Pure memory-bound band gather (~35.6 MB total traffic).
//
// v2: fully ALIGNED memory traffic. One wave per row; lane ln owns out float4
// at j = 4*ln. Row misalignment s = i & 3 is wave-uniform, so each lane loads
// the 16B-aligned chunk C_ln covering floats [a0+4*ln, a0+4*ln+3] (a0 = i-s),
// grabs its neighbor's chunk via __shfl_down, and recombines the s-float shift
// with a uniform switch. Lane 63's neighbor is the extra chunk at a0+256,
// fetched as a wave-uniform broadcast load (1 line). Stores are aligned float4,
// nontemporal (output never re-read). Tail rows (i > L-260) take the old
// predicated-scalar path which never reads past x[b, i, L-1].

constexpr int B_SZ  = 4;
constexpr int L_DIM = 4096;
constexpr int LIMIT = 256;

typedef float float4a __attribute__((ext_vector_type(4), aligned(16)));

__global__ __launch_bounds__(256) void band_gather_kernel(
    const float* __restrict__ x, float* __restrict__ out) {
    const int t  = blockIdx.x * blockDim.x + threadIdx.x;
    // t in [0, B*L*(LIMIT/4)) = [0, 1048576)
    const int ln = t & 63;                  // lane within wave = j-group
    const int i  = (t >> 6) & (L_DIM - 1);  // row (wave-uniform)
    const int b  = t >> 18;                 // batch

    const size_t row = (size_t)b * L_DIM + i;
    const float* __restrict__ xrow = x + row * (size_t)L_DIM;

    const int s  = i & 3;   // wave-uniform shift in floats
    const int a0 = i - s;   // 16B-aligned band start (row base is 16KB-aligned)

    float4a v;

    if (i + 260 <= L_DIM) {
        // Fast path: band + 1 spare chunk fully inside the row.
        // Aligned 16B load, perfectly wave-coalesced (contiguous 1KiB+16B).
        const float4a C =
            __builtin_nontemporal_load((const float4a*)(xrow + a0) + ln);

        if (s == 0) {
            v = C;
        } else {
            // Neighbor lane's chunk; lane 63 needs the 65th chunk instead.
            float4a N;
            N.x = __shfl_down(C.x, 1);
            N.y = __shfl_down(C.y, 1);
            N.z = __shfl_down(C.z, 1);
            N.w = __shfl_down(C.w, 1);
            const float4a E =
                __builtin_nontemporal_load((const float4a*)(xrow + a0) + 64);
            if (ln == 63) N = E;  // wave-uniform broadcast chunk

            switch (s) {  // wave-uniform branch
                case 1:  v = (float4a){C.y, C.z, C.w, N.x}; break;
                case 2:  v = (float4a){C.z, C.w, N.x, N.y}; break;
                default: v = (float4a){C.w, N.x, N.y, N.z}; break;
            }
        }
    } else {
        // Tail rows (last 259 per batch): predicated scalar gather,
        // never reads past x[b, i, L-1].
        const int j4   = ln << 2;
        const int base = i + j4;
        const int lim  = L_DIM - i;  // valid while j < lim
        v.x = (j4 + 0 < lim) ? xrow[base + 0] : 0.0f;
        v.y = (j4 + 1 < lim) ? xrow[base + 1] : 0.0f;
        v.z = (j4 + 2 < lim) ? xrow[base + 2] : 0.0f;
        v.w = (j4 + 3 < lim) ? xrow[base + 3] : 0.0f;
    }

    float4a* __restrict__ orow = (float4a*)(out + row * (size_t)LIMIT);
    __builtin_nontemporal_store(v, orow + ln);
}

extern "C" void kernel_launch(void* const* d_in, const int* in_sizes, int n_in,
                              void* d_out, int out_size, void* d_ws, size_t ws_size,
                              hipStream_t stream) {
    const float* x = (const float*)d_in[0];
    float* out = (float*)d_out;

    const int total_threads = B_SZ * L_DIM * (LIMIT / 4); // 1,048,576
    const int block = 256;
    const int grid = total_threads / block;               // 4096
    band_gather_kernel<<<grid, block, 0, stream>>>(x, out);
}